// Round 3
// baseline (10798.638 us; speedup 1.0000x reference)
//
#include <hip/hip_runtime.h>
#include <math.h>

#define Bb 256
#define Ii 128
#define Tt 256
#define Hh 512
#define Oo 2
#define TBr (Tt*Bb)
#define EPS_BN 1e-5f
#define NBLK 128
#define NTHR 512

typedef __attribute__((ext_vector_type(8))) short short8;
typedef __attribute__((ext_vector_type(8))) __bf16 bf16x8;
typedef __attribute__((ext_vector_type(4))) float f32x4;

__device__ __forceinline__ f32x4 mfma_bf16(short8 a, short8 b, f32x4 c) {
    return __builtin_amdgcn_mfma_f32_16x16x32_bf16(
        __builtin_bit_cast(bf16x8, a), __builtin_bit_cast(bf16x8, b), c, 0, 0, 0);
}
__device__ __forceinline__ short f2bf(float f) {
    union { float f; unsigned u; } v; v.f = f;
    unsigned r = (v.u + 0x7FFFu + ((v.u >> 16) & 1u)) >> 16;
    return (short)r;
}
__device__ __forceinline__ float bf2f(short s) {
    union { unsigned u; float f; } v; v.u = ((unsigned)(unsigned short)s) << 16;
    return v.f;
}
__device__ __forceinline__ float sigmoidf_(float x) { return 1.f / (1.f + expf(-x)); }
__device__ __forceinline__ float softplusf_(float x) { return fmaxf(x, 0.f) + log1pf(expf(-fabsf(x))); }

// ---------------------------------------------------------------------------
// repack: input [B,3,I,T] fp32 -> time-major X fp32 [T,B,I], M bf16, D bf16
// ---------------------------------------------------------------------------
__global__ __launch_bounds__(1024) void repack_kernel(const float* __restrict__ in,
                                                      float* __restrict__ Xall,
                                                      short* __restrict__ Mall,
                                                      short* __restrict__ Dall)
{
    __shared__ float tile[32][33];
    const int bz = blockIdx.z;
    const int b = bz / 3, cch = bz % 3;
    const int t0 = blockIdx.x * 32, i0 = blockIdx.y * 32;
    const int tx = threadIdx.x, ty = threadIdx.y;
    const float* src = in + ((size_t)b * 3 + cch) * (size_t)Ii * Tt;
    tile[ty][tx] = src[(size_t)(i0 + ty) * Tt + t0 + tx];
    __syncthreads();
    const float v = tile[tx][ty];
    const size_t off = ((size_t)(t0 + ty) * Bb + b) * Ii + i0 + tx;
    if (cch == 0)      Xall[off] = v;
    else if (cch == 1) Mall[off] = f2bf(v);
    else               Dall[off] = f2bf(v);
}

// ---------------------------------------------------------------------------
// pack weights -> bf16 transposed (n-major, k rows) for MFMA B fragments
// ---------------------------------------------------------------------------
__global__ __launch_bounds__(256) void pack_weights_kernel(
    const float* __restrict__ W_dg_x, const float* __restrict__ W_dg_h,
    const float* __restrict__ W_xz, const float* __restrict__ W_hz, const float* __restrict__ W_mz, const float* __restrict__ b_z,
    const float* __restrict__ W_xr, const float* __restrict__ W_hr, const float* __restrict__ W_mr, const float* __restrict__ b_r,
    const float* __restrict__ W_xh, const float* __restrict__ W_hh, const float* __restrict__ W_mh,
    short* __restrict__ Wc1T, short* __restrict__ Wc2T,
    short* __restrict__ WdgxT, short* __restrict__ WdghT, float* __restrict__ bias1)
{
    const int idx = blockIdx.x * blockDim.x + threadIdx.x;
    const int n1 = 1024 * 768, n2 = 512 * 768, n3 = 128 * 128, n4 = 512 * 128;
    if (idx < n1) {
        const int n = idx / 768, k = idx % 768;
        const int col = (n < Hh) ? n : (n - Hh);
        const float* Wx = (n < Hh) ? W_xz : W_xr;
        const float* Wm = (n < Hh) ? W_mz : W_mr;
        const float* Wh = (n < Hh) ? W_hz : W_hr;
        float v;
        if (k < Ii)        v = Wx[(size_t)k * Hh + col];
        else if (k < 2*Ii) v = Wm[(size_t)(k - Ii) * Hh + col];
        else               v = Wh[(size_t)(k - 2*Ii) * Hh + col];
        Wc1T[idx] = f2bf(v);
    } else if (idx < n1 + n2) {
        const int j = idx - n1;
        const int n = j / 768, k = j % 768;
        float v;
        if (k < Ii)        v = W_xh[(size_t)k * Hh + n];
        else if (k < 2*Ii) v = W_mh[(size_t)(k - Ii) * Hh + n];
        else               v = W_hh[(size_t)(k - 2*Ii) * Hh + n];
        Wc2T[j] = f2bf(v);
    } else if (idx < n1 + n2 + n3) {
        const int j = idx - n1 - n2;
        const int n = j >> 7, k = j & 127;
        WdgxT[j] = f2bf(W_dg_x[(size_t)k * Ii + n]);
    } else if (idx < n1 + n2 + n3 + n4) {
        const int j = idx - n1 - n2 - n3;
        const int n = j >> 7, k = j & 127;
        WdghT[j] = f2bf(W_dg_h[(size_t)k * Hh + n]);
    } else if (idx < n1 + n2 + n3 + n4 + 1024) {
        const int n = idx - n1 - n2 - n3 - n4;
        bias1[n] = (n < Hh) ? b_z[n] : b_r[n - Hh];
    }
}

// ---------------------------------------------------------------------------
// gdecay: C = bf16(exp(-relu(A @ B + bias)))  A bf16 [M][128], BT bf16 [N][128]
// ---------------------------------------------------------------------------
__global__ __launch_bounds__(64) void gdecay_kernel(const short* __restrict__ A,
                                                    const short* __restrict__ BT,
                                                    const float* __restrict__ bias,
                                                    short* __restrict__ C, int N)
{
    const int lane = threadIdx.x;
    const int c = lane & 15, g = lane >> 4;
    const int m0 = blockIdx.x * 32, n0 = blockIdx.y * 64;
    const short* a0 = A + (size_t)(m0 + c) * Ii + 8 * g;
    const short* a1 = a0 + (size_t)16 * Ii;
    const short* bw = BT + (size_t)(n0 + c) * Ii + 8 * g;
    f32x4 acc[2][4];
    #pragma unroll
    for (int i = 0; i < 2; ++i)
        #pragma unroll
        for (int f = 0; f < 4; ++f) acc[i][f] = (f32x4){0.f, 0.f, 0.f, 0.f};
    #pragma unroll
    for (int k0 = 0; k0 < 128; k0 += 32) {
        const short8 av0 = *(const short8*)(a0 + k0);
        const short8 av1 = *(const short8*)(a1 + k0);
        #pragma unroll
        for (int fn = 0; fn < 4; ++fn) {
            const short8 bv = *(const short8*)(bw + (size_t)fn * 16 * Ii + k0);
            acc[0][fn] = mfma_bf16(av0, bv, acc[0][fn]);
            acc[1][fn] = mfma_bf16(av1, bv, acc[1][fn]);
        }
    }
    #pragma unroll
    for (int fn = 0; fn < 4; ++fn) {
        const int n = n0 + fn * 16 + c;
        const float bs = bias[n];
        #pragma unroll
        for (int fm = 0; fm < 2; ++fm) {
            #pragma unroll
            for (int j = 0; j < 4; ++j) {
                const int m = m0 + fm * 16 + 4 * g + j;
                const float v = expf(-fmaxf(acc[fm][fn][j] + bs, 0.f));
                C[(size_t)m * N + n] = f2bf(v);
            }
        }
    }
}

// ---------------------------------------------------------------------------
// x_last scan + x_eff -> Xe bf16 [T,B,I]
// ---------------------------------------------------------------------------
__global__ __launch_bounds__(256) void xeff_scan_kernel(const float* __restrict__ Xall,
                                                        const short* __restrict__ Mall,
                                                        const short* __restrict__ Gx,
                                                        const float* __restrict__ xmean_p,
                                                        short* __restrict__ Xe)
{
    const int bi = blockIdx.x * blockDim.x + threadIdx.x;
    if (bi >= Bb * Ii) return;
    const float xm = xmean_p[0];
    float xl = 0.f;
    for (int t = 0; t < Tt; ++t) {
        const size_t off = (size_t)t * Bb * Ii + bi;
        const float x = Xall[off];
        const float m = bf2f(Mall[off]);
        const float gx = bf2f(Gx[off]);
        if (m > 0.f) xl = x;
        Xe[off] = f2bf(m * x + (1.f - m) * (gx * xl + (1.f - gx) * xm));
    }
}

// ---------------------------------------------------------------------------
// device-wide monotonic-counter barrier (all NBLK blocks co-resident)
// ---------------------------------------------------------------------------
__device__ __forceinline__ void gbar(int* cnt, int epoch) {
    __syncthreads();                 // drains vmcnt -> block's stores are in L2
    if (threadIdx.x == 0) {
        __hip_atomic_fetch_add(cnt, 1, __ATOMIC_RELEASE, __HIP_MEMORY_SCOPE_AGENT);
        const int target = epoch * NBLK;
        while (__hip_atomic_load(cnt, __ATOMIC_RELAXED, __HIP_MEMORY_SCOPE_AGENT) < target)
            __builtin_amdgcn_s_sleep(4);
        (void)__hip_atomic_load(cnt, __ATOMIC_ACQUIRE, __HIP_MEMORY_SCOPE_AGENT);
    }
    __syncthreads();
}

// ---------------------------------------------------------------------------
// persistent kernel: all 256 time steps, 3 device barriers per step
// ---------------------------------------------------------------------------
__global__ __launch_bounds__(NTHR, 1) void grud_persistent(
    const short* __restrict__ Xe, const short* __restrict__ Ma,
    const short* __restrict__ Ghb,
    const short* __restrict__ Wc1T, const short* __restrict__ Wc2T,
    const float* __restrict__ bias1, const float* __restrict__ b_h,
    const float* __restrict__ bn_g, const float* __restrict__ bn_b,
    const float* __restrict__ Why, const float* __restrict__ bhy,
    float* __restrict__ Zbuf, short* __restrict__ RH,
    short* __restrict__ Hp, float* __restrict__ Hraw,
    float* __restrict__ Ssum, float* __restrict__ Ssq,   // each [2][512]
    float* __restrict__ out_hs, float* __restrict__ out_ys,
    int* __restrict__ barcnt)
{
    const int b = blockIdx.x;
    const int tid = threadIdx.x;
    const int w = tid >> 6, lane = tid & 63;
    const int c = lane & 15, g = lane >> 4;
    const int q = w & 3;

    __shared__ float lds[8][64][16];   // 32 KB k-split reduce scratch

    int epoch = 0;

    for (int t = 0; t < Tt; ++t) {
        const int par = t & 1;
        float* Ssum_p = Ssum + par * Hh;
        float* Ssq_p  = Ssq  + par * Hh;

        // ---- duties at top of phase A ----
        // zero this step's BN stat buffers (filled by phase B after barrier 1)
        if (b == 0) Ssum_p[tid] = 0.f;
        if (b == 1) Ssq_p[tid] = 0.f;
        // y[t-1] from out_hs (written by C[t-1], visible after barrier 3)
        if (q == 0 && t > 0) {
            const int row = 2 * b + (w >> 2);
            const float* hsrc = out_hs + ((size_t)row * Tt + (t - 1)) * Hh;
            float p0 = 0.f, p1 = 0.f;
            #pragma unroll
            for (int i = 0; i < 8; ++i) {
                const int n = lane + i * 64;
                const float h = hsrc[n];
                p0 += h * Why[2 * n];
                p1 += h * Why[2 * n + 1];
            }
            #pragma unroll
            for (int s = 1; s < 64; s <<= 1) { p0 += __shfl_xor(p0, s); p1 += __shfl_xor(p1, s); }
            if (lane == 0) {
                out_ys[((size_t)row * Tt + (t - 1)) * Oo + 0] = softplusf_(p0 + bhy[0]);
                out_ys[((size_t)row * Tt + (t - 1)) * Oo + 1] = softplusf_(p1 + bhy[1]);
            }
        }

        // ================= Phase A : z|r GEMM (M=256,N=1024,K=768) =========
        {
            const int tau = 2 * b + (w >> 2);         // 0..255
            const int mt = tau & 15, nt = tau >> 4;
            const int m0 = mt * 16, n0 = nt * 64;
            const short* arow_xe = Xe + ((size_t)t * Bb + m0 + c) * Ii + 8 * g;
            const short* arow_m  = Ma + ((size_t)t * Bb + m0 + c) * Ii + 8 * g;
            const short* arow_h  = Hp + (size_t)(m0 + c) * Hh + 8 * g;
            const short* bw = Wc1T + (size_t)(n0 + c) * 768 + 8 * g;
            f32x4 acc[4];
            #pragma unroll
            for (int f = 0; f < 4; ++f) acc[f] = (f32x4){0.f, 0.f, 0.f, 0.f};
            const int kbase = q * 192;
            #pragma unroll
            for (int s = 0; s < 6; ++s) {
                const int k = kbase + 32 * s;
                const short* ap = (k < 128) ? (arow_xe + k)
                                : (k < 256) ? (arow_m + (k - 128))
                                            : (arow_h + (k - 256));
                const short8 a = *(const short8*)ap;
                #pragma unroll
                for (int fn = 0; fn < 4; ++fn) {
                    const short8 bb = *(const short8*)(bw + (size_t)fn * 16 * 768 + k);
                    acc[fn] = mfma_bf16(a, bb, acc[fn]);
                }
            }
            #pragma unroll
            for (int fn = 0; fn < 4; ++fn)
                #pragma unroll
                for (int j = 0; j < 4; ++j) lds[w][lane][fn * 4 + j] = acc[fn][j];
            __syncthreads();
            if (q == 0) {
                #pragma unroll
                for (int fn = 0; fn < 4; ++fn)
                    #pragma unroll
                    for (int j = 0; j < 4; ++j)
                        acc[fn][j] += lds[w + 1][lane][fn * 4 + j]
                                    + lds[w + 2][lane][fn * 4 + j]
                                    + lds[w + 3][lane][fn * 4 + j];
                #pragma unroll
                for (int fn = 0; fn < 4; ++fn) {
                    const int n = n0 + fn * 16 + c;
                    const float bs = bias1[n];
                    #pragma unroll
                    for (int j = 0; j < 4; ++j) {
                        const int m = m0 + 4 * g + j;
                        const float v = sigmoidf_(acc[fn][j] + bs);
                        if (n < Hh) {
                            Zbuf[(size_t)m * Hh + n] = v;
                        } else {
                            const int nn = n - Hh;
                            RH[(size_t)m * Hh + nn] = f2bf(v * bf2f(Hp[(size_t)m * Hh + nn]));
                        }
                    }
                }
            }
        }
        gbar(barcnt, ++epoch);   // barrier 1: RH/Zbuf/stat-zero ready

        // ================= Phase B : h~ GEMM (M=256,N=512,K=768) ===========
        {
            const int tau = 2 * b + (w >> 2);         // 0..255, tiles 16x32
            const int mt = tau & 15, nt = tau >> 4;
            const int m0 = mt * 16, n0 = nt * 32;
            const short* arow_xe = Xe + ((size_t)t * Bb + m0 + c) * Ii + 8 * g;
            const short* arow_m  = Ma + ((size_t)t * Bb + m0 + c) * Ii + 8 * g;
            const short* arow_r  = RH + (size_t)(m0 + c) * Hh + 8 * g;
            const short* bw = Wc2T + (size_t)(n0 + c) * 768 + 8 * g;
            f32x4 acc[2];
            acc[0] = (f32x4){0.f, 0.f, 0.f, 0.f};
            acc[1] = (f32x4){0.f, 0.f, 0.f, 0.f};
            const int kbase = q * 192;
            #pragma unroll
            for (int s = 0; s < 6; ++s) {
                const int k = kbase + 32 * s;
                const short* ap = (k < 128) ? (arow_xe + k)
                                : (k < 256) ? (arow_m + (k - 128))
                                            : (arow_r + (k - 256));
                const short8 a = *(const short8*)ap;
                #pragma unroll
                for (int fn = 0; fn < 2; ++fn) {
                    const short8 bb = *(const short8*)(bw + (size_t)fn * 16 * 768 + k);
                    acc[fn] = mfma_bf16(a, bb, acc[fn]);
                }
            }
            #pragma unroll
            for (int fn = 0; fn < 2; ++fn)
                #pragma unroll
                for (int j = 0; j < 4; ++j) lds[w][lane][fn * 4 + j] = acc[fn][j];
            __syncthreads();
            if (q == 0) {
                #pragma unroll
                for (int fn = 0; fn < 2; ++fn)
                    #pragma unroll
                    for (int j = 0; j < 4; ++j)
                        acc[fn][j] += lds[w + 1][lane][fn * 4 + j]
                                    + lds[w + 2][lane][fn * 4 + j]
                                    + lds[w + 3][lane][fn * 4 + j];
                #pragma unroll
                for (int fn = 0; fn < 2; ++fn) {
                    const int n = n0 + fn * 16 + c;
                    const float bs = b_h[n];
                    float sp = 0.f, sq = 0.f;
                    #pragma unroll
                    for (int j = 0; j < 4; ++j) {
                        const int m = m0 + 4 * g + j;
                        const float pre = acc[fn][j] + bs;
                        const float z = Zbuf[(size_t)m * Hh + n];
                        const float hp = bf2f(Hp[(size_t)m * Hh + n]);
                        const float hr = (1.f - z) * hp + z * tanhf(pre);
                        Hraw[(size_t)m * Hh + n] = hr;
                        sp += hr; sq += hr * hr;
                    }
                    sp += __shfl_xor(sp, 16); sp += __shfl_xor(sp, 32);
                    sq += __shfl_xor(sq, 16); sq += __shfl_xor(sq, 32);
                    if (g == 0) {
                        atomicAdd(&Ssum_p[n], sp);
                        atomicAdd(&Ssq_p[n], sq);
                    }
                }
            }
        }
        gbar(barcnt, ++epoch);   // barrier 2: Hraw + BN stats complete

        // ================= Phase C : BN apply + outputs ====================
        {
            const int gid = b * NTHR + tid;           // 0..65535
            #pragma unroll
            for (int i = 0; i < 2; ++i) {
                const int e = gid + i * 65536;
                const int r = e >> 9, n = e & 511;
                const float mu = Ssum_p[n] * (1.f / Bb);
                const float var = fmaxf(Ssq_p[n] * (1.f / Bb) - mu * mu, 0.f);
                const float rstd = rsqrtf(var + EPS_BN);
                const float sc = bn_g[n] * rstd;
                const float sh = bn_b[n] - mu * sc;
                const float h = sc * Hraw[(size_t)r * Hh + n] + sh;
                out_hs[((size_t)r * Tt + t) * Hh + n] = h;
                if (t + 1 < Tt) {
                    const float gh = bf2f(Ghb[((size_t)(t + 1) * Bb + r) * Hh + n]);
                    Hp[(size_t)r * Hh + n] = f2bf(h * gh);
                }
            }
        }
        gbar(barcnt, ++epoch);   // barrier 3: Hp / out_hs ready
    }

    // final y for t = Tt-1
    if (q == 0) {
        const int row = 2 * b + (w >> 2);
        const float* hsrc = out_hs + ((size_t)row * Tt + (Tt - 1)) * Hh;
        float p0 = 0.f, p1 = 0.f;
        #pragma unroll
        for (int i = 0; i < 8; ++i) {
            const int n = lane + i * 64;
            const float h = hsrc[n];
            p0 += h * Why[2 * n];
            p1 += h * Why[2 * n + 1];
        }
        #pragma unroll
        for (int s = 1; s < 64; s <<= 1) { p0 += __shfl_xor(p0, s); p1 += __shfl_xor(p1, s); }
        if (lane == 0) {
            out_ys[((size_t)row * Tt + (Tt - 1)) * Oo + 0] = softplusf_(p0 + bhy[0]);
            out_ys[((size_t)row * Tt + (Tt - 1)) * Oo + 1] = softplusf_(p1 + bhy[1]);
        }
    }
}

// ---------------------------------------------------------------------------
extern "C" void kernel_launch(void* const* d_in, const int* in_sizes, int n_in,
                              void* d_out, int out_size, void* d_ws, size_t ws_size,
                              hipStream_t stream)
{
    const float* input  = (const float*)d_in[0];
    const float* xmean  = (const float*)d_in[1];
    const float* W_dg_x = (const float*)d_in[2];
    const float* b_dg_x = (const float*)d_in[3];
    const float* W_dg_h = (const float*)d_in[4];
    const float* b_dg_h = (const float*)d_in[5];
    const float* W_xz   = (const float*)d_in[6];
    const float* W_hz   = (const float*)d_in[7];
    const float* W_mz   = (const float*)d_in[8];
    const float* b_z    = (const float*)d_in[9];
    const float* W_xr   = (const float*)d_in[10];
    const float* W_hr   = (const float*)d_in[11];
    const float* W_mr   = (const float*)d_in[12];
    const float* b_r    = (const float*)d_in[13];
    const float* W_xh   = (const float*)d_in[14];
    const float* W_hh   = (const float*)d_in[15];
    const float* W_mh   = (const float*)d_in[16];
    const float* b_h    = (const float*)d_in[17];
    const float* W_hy   = (const float*)d_in[18];
    const float* b_hy   = (const float*)d_in[19];
    const float* bn_g   = (const float*)d_in[20];
    const float* bn_b   = (const float*)d_in[21];

    float* out_ys = (float*)d_out;
    float* out_hs = out_ys + (size_t)Bb * Tt * Oo;

    char* p = (char*)d_ws;
    float* Xall = (float*)p;            p += (size_t)TBr * Ii * 4;
    short* Mall = (short*)p;            p += (size_t)TBr * Ii * 2;
    short* Dall = (short*)p;            p += (size_t)TBr * Ii * 2;
    short* Gxb  = (short*)p;            p += (size_t)TBr * Ii * 2;
    short* Ghb  = (short*)p;            p += (size_t)TBr * Hh * 2;
    short* Xe   = (short*)p;            p += (size_t)TBr * Ii * 2;
    short* Wc1T = (short*)p;            p += (size_t)1024 * 768 * 2;
    short* Wc2T = (short*)p;            p += (size_t)512 * 768 * 2;
    short* WdgxT= (short*)p;            p += (size_t)128 * 128 * 2;
    short* WdghT= (short*)p;            p += (size_t)512 * 128 * 2;
    float* bias1= (float*)p;            p += 1024 * 4;
    float* Zbuf = (float*)p;            p += (size_t)Bb * Hh * 4;
    short* RH   = (short*)p;            p += (size_t)Bb * Hh * 2;
    short* Hp   = (short*)p;            p += (size_t)Bb * Hh * 2;
    float* Hraw = (float*)p;            p += (size_t)Bb * Hh * 4;
    float* Ssum = (float*)p;            p += 2 * Hh * 4;
    float* Ssq  = (float*)p;            p += 2 * Hh * 4;
    int*   barcnt = (int*)p;            p += 256;

    hipMemsetAsync(Hp, 0, (size_t)Bb * Hh * 2, stream);
    hipMemsetAsync(barcnt, 0, 256, stream);

    repack_kernel<<<dim3(Tt / 32, Ii / 32, Bb * 3), dim3(32, 32), 0, stream>>>(input, Xall, Mall, Dall);

    {
        const int total = 1024 * 768 + 512 * 768 + 128 * 128 + 512 * 128 + 1024;
        pack_weights_kernel<<<(total + 255) / 256, 256, 0, stream>>>(
            W_dg_x, W_dg_h,
            W_xz, W_hz, W_mz, b_z,
            W_xr, W_hr, W_mr, b_r,
            W_xh, W_hh, W_mh,
            Wc1T, Wc2T, WdgxT, WdghT, bias1);
    }

    gdecay_kernel<<<dim3(TBr / 32, Ii / 64), 64, 0, stream>>>(Dall, WdgxT, b_dg_x, Gxb, Ii);
    gdecay_kernel<<<dim3(TBr / 32, Hh / 64), 64, 0, stream>>>(Dall, WdghT, b_dg_h, Ghb, Hh);

    xeff_scan_kernel<<<(Bb * Ii) / 256, 256, 0, stream>>>(Xall, Mall, Gxb, xmean, Xe);

    grud_persistent<<<NBLK, NTHR, 0, stream>>>(
        Xe, Mall, Ghb, Wc1T, Wc2T, bias1, b_h, bn_g, bn_b,
        W_hy, b_hy, Zbuf, RH, Hp, Hraw, Ssum, Ssq,
        out_hs, out_ys, barcnt);
}

// Round 4
// 6088.662 us; speedup vs baseline: 1.7736x; 1.7736x over previous
//
#include <hip/hip_runtime.h>
#include <math.h>

#define Bb 256
#define Ii 128
#define Tt 256
#define Hh 512
#define Oo 2
#define TBr (Tt*Bb)
#define EPS_BN 1e-5f

typedef __attribute__((ext_vector_type(8))) short short8;
typedef __attribute__((ext_vector_type(8))) __bf16 bf16x8;
typedef __attribute__((ext_vector_type(4))) float f32x4;

__device__ __forceinline__ f32x4 mfma_bf16(short8 a, short8 b, f32x4 c) {
    return __builtin_amdgcn_mfma_f32_16x16x32_bf16(
        __builtin_bit_cast(bf16x8, a), __builtin_bit_cast(bf16x8, b), c, 0, 0, 0);
}
__device__ __forceinline__ short f2bf(float f) {
    union { float f; unsigned u; } v; v.f = f;
    unsigned r = (v.u + 0x7FFFu + ((v.u >> 16) & 1u)) >> 16;
    return (short)r;
}
__device__ __forceinline__ float bf2f(short s) {
    union { unsigned u; float f; } v; v.u = ((unsigned)(unsigned short)s) << 16;
    return v.f;
}
__device__ __forceinline__ float sigmoidf_(float x) { return 1.f / (1.f + expf(-x)); }
__device__ __forceinline__ float softplusf_(float x) { return fmaxf(x, 0.f) + log1pf(expf(-fabsf(x))); }

// ---------------------------------------------------------------------------
// repack: input [B,3,I,T] fp32 -> time-major X fp32 [T,B,I], M bf16, D bf16
// ---------------------------------------------------------------------------
__global__ __launch_bounds__(1024) void repack_kernel(const float* __restrict__ in,
                                                      float* __restrict__ Xall,
                                                      short* __restrict__ Mall,
                                                      short* __restrict__ Dall)
{
    __shared__ float tile[32][33];
    const int bz = blockIdx.z;
    const int b = bz / 3, cch = bz % 3;
    const int t0 = blockIdx.x * 32, i0 = blockIdx.y * 32;
    const int tx = threadIdx.x, ty = threadIdx.y;
    const float* src = in + ((size_t)b * 3 + cch) * (size_t)Ii * Tt;
    tile[ty][tx] = src[(size_t)(i0 + ty) * Tt + t0 + tx];
    __syncthreads();
    const float v = tile[tx][ty];
    const size_t off = ((size_t)(t0 + ty) * Bb + b) * Ii + i0 + tx;
    if (cch == 0)      Xall[off] = v;
    else if (cch == 1) Mall[off] = f2bf(v);
    else               Dall[off] = f2bf(v);
}

// ---------------------------------------------------------------------------
// pack weights -> bf16 transposed (n-major, k rows) for MFMA B fragments
// ---------------------------------------------------------------------------
__global__ __launch_bounds__(256) void pack_weights_kernel(
    const float* __restrict__ W_dg_x, const float* __restrict__ W_dg_h,
    const float* __restrict__ W_xz, const float* __restrict__ W_hz, const float* __restrict__ W_mz, const float* __restrict__ b_z,
    const float* __restrict__ W_xr, const float* __restrict__ W_hr, const float* __restrict__ W_mr, const float* __restrict__ b_r,
    const float* __restrict__ W_xh, const float* __restrict__ W_hh, const float* __restrict__ W_mh,
    short* __restrict__ Wc1T, short* __restrict__ Wc2T,
    short* __restrict__ WdgxT, short* __restrict__ WdghT, float* __restrict__ bias1)
{
    const int idx = blockIdx.x * blockDim.x + threadIdx.x;
    const int n1 = 1024 * 768, n2 = 512 * 768, n3 = 128 * 128, n4 = 512 * 128;
    if (idx < n1) {
        const int n = idx / 768, k = idx % 768;
        const int col = (n < Hh) ? n : (n - Hh);
        const float* Wx = (n < Hh) ? W_xz : W_xr;
        const float* Wm = (n < Hh) ? W_mz : W_mr;
        const float* Wh = (n < Hh) ? W_hz : W_hr;
        float v;
        if (k < Ii)        v = Wx[(size_t)k * Hh + col];
        else if (k < 2*Ii) v = Wm[(size_t)(k - Ii) * Hh + col];
        else               v = Wh[(size_t)(k - 2*Ii) * Hh + col];
        Wc1T[idx] = f2bf(v);
    } else if (idx < n1 + n2) {
        const int j = idx - n1;
        const int n = j / 768, k = j % 768;
        float v;
        if (k < Ii)        v = W_xh[(size_t)k * Hh + n];
        else if (k < 2*Ii) v = W_mh[(size_t)(k - Ii) * Hh + n];
        else               v = W_hh[(size_t)(k - 2*Ii) * Hh + n];
        Wc2T[j] = f2bf(v);
    } else if (idx < n1 + n2 + n3) {
        const int j = idx - n1 - n2;
        const int n = j >> 7, k = j & 127;
        WdgxT[j] = f2bf(W_dg_x[(size_t)k * Ii + n]);
    } else if (idx < n1 + n2 + n3 + n4) {
        const int j = idx - n1 - n2 - n3;
        const int n = j >> 7, k = j & 127;
        WdghT[j] = f2bf(W_dg_h[(size_t)k * Hh + n]);
    } else if (idx < n1 + n2 + n3 + n4 + 1024) {
        const int n = idx - n1 - n2 - n3 - n4;
        bias1[n] = (n < Hh) ? b_z[n] : b_r[n - Hh];
    }
}

// ---------------------------------------------------------------------------
// gdecay: C = bf16(exp(-relu(A @ B + bias)))  A bf16 [M][128], BT bf16 [N][128]
// ---------------------------------------------------------------------------
__global__ __launch_bounds__(64) void gdecay_kernel(const short* __restrict__ A,
                                                    const short* __restrict__ BT,
                                                    const float* __restrict__ bias,
                                                    short* __restrict__ C, int N)
{
    const int lane = threadIdx.x;
    const int c = lane & 15, g = lane >> 4;
    const int m0 = blockIdx.x * 32, n0 = blockIdx.y * 64;
    const short* a0 = A + (size_t)(m0 + c) * Ii + 8 * g;
    const short* a1 = a0 + (size_t)16 * Ii;
    const short* bw = BT + (size_t)(n0 + c) * Ii + 8 * g;
    f32x4 acc[2][4];
    #pragma unroll
    for (int i = 0; i < 2; ++i)
        #pragma unroll
        for (int f = 0; f < 4; ++f) acc[i][f] = (f32x4){0.f, 0.f, 0.f, 0.f};
    #pragma unroll
    for (int k0 = 0; k0 < 128; k0 += 32) {
        const short8 av0 = *(const short8*)(a0 + k0);
        const short8 av1 = *(const short8*)(a1 + k0);
        #pragma unroll
        for (int fn = 0; fn < 4; ++fn) {
            const short8 bv = *(const short8*)(bw + (size_t)fn * 16 * Ii + k0);
            acc[0][fn] = mfma_bf16(av0, bv, acc[0][fn]);
            acc[1][fn] = mfma_bf16(av1, bv, acc[1][fn]);
        }
    }
    #pragma unroll
    for (int fn = 0; fn < 4; ++fn) {
        const int n = n0 + fn * 16 + c;
        const float bs = bias[n];
        #pragma unroll
        for (int fm = 0; fm < 2; ++fm) {
            #pragma unroll
            for (int j = 0; j < 4; ++j) {
                const int m = m0 + fm * 16 + 4 * g + j;
                const float v = expf(-fmaxf(acc[fm][fn][j] + bs, 0.f));
                C[(size_t)m * N + n] = f2bf(v);
            }
        }
    }
}

// ---------------------------------------------------------------------------
// x_last scan + x_eff -> Xe bf16 [T,B,I]
// ---------------------------------------------------------------------------
__global__ __launch_bounds__(256) void xeff_scan_kernel(const float* __restrict__ Xall,
                                                        const short* __restrict__ Mall,
                                                        const short* __restrict__ Gx,
                                                        const float* __restrict__ xmean_p,
                                                        short* __restrict__ Xe)
{
    const int bi = blockIdx.x * blockDim.x + threadIdx.x;
    if (bi >= Bb * Ii) return;
    const float xm = xmean_p[0];
    float xl = 0.f;
    for (int t = 0; t < Tt; ++t) {
        const size_t off = (size_t)t * Bb * Ii + bi;
        const float x = Xall[off];
        const float m = bf2f(Mall[off]);
        const float gx = bf2f(Gx[off]);
        if (m > 0.f) xl = x;
        Xe[off] = f2bf(m * x + (1.f - m) * (gx * xl + (1.f - gx) * xm));
    }
}

// ---------------------------------------------------------------------------
// persistent kernel: 256 blocks x 512 threads, 2 flag-array barriers/step
// block (mt = bid&15, ng = bid>>4); weights cached in registers
// ---------------------------------------------------------------------------
__global__ __launch_bounds__(512, 2) void grud_persistent(
    const short* __restrict__ Xe, const short* __restrict__ Ma,
    const short* __restrict__ Ghb,
    const short* __restrict__ Wc1T, const short* __restrict__ Wc2T,
    const float* __restrict__ bias1, const float* __restrict__ b_h,
    const float* __restrict__ bn_g, const float* __restrict__ bn_b,
    const float* __restrict__ Why, const float* __restrict__ bhy,
    float* __restrict__ Zbuf, short* __restrict__ RH,
    float* __restrict__ Hraw,          // [2][256][512]
    float* __restrict__ Pst,           // [2][2][16][512] BN partials
    float* __restrict__ out_hs, float* __restrict__ out_ys,
    int* __restrict__ barr)
{
    const int bid = blockIdx.x, tid = threadIdx.x;
    const int w = tid >> 6, lane = tid & 63, c = lane & 15, g = lane >> 4;
    const int mt = bid & 15, ng = bid >> 4;
    const int m0 = mt * 16;
    const int aA = w & 3, kh = w >> 2;        // phase A role
    const int n0A = ng * 64 + aA * 16;
    const int bB = w & 1, kq = w >> 1;        // phase B role
    const int n0B = ng * 32 + bB * 16;

    __shared__ short sXM[16 * 256];           // [Xe|Ma] tile, 8 KB
    __shared__ short sH[16 * 512];            // hp tile, 16 KB
    __shared__ short sRH[16 * 512];           // r*hp tile, 16 KB
    __shared__ float scratch[1536];           // k-split reduce, 6 KB
    __shared__ float scs[512], shs[512];      // BN scale/shift
    __shared__ float ysred[16];

    // preload weight fragments into registers (constant across all steps)
    short8 wA[12];
    {
        const short* bw = Wc1T + (size_t)(n0A + c) * 768 + 8 * g + kh * 384;
        #pragma unroll
        for (int s = 0; s < 12; ++s) wA[s] = *(const short8*)(bw + 32 * s);
    }
    short8 wB[6];
    {
        const short* bw = Wc2T + (size_t)(n0B + c) * 768 + 8 * g + kq * 192;
        #pragma unroll
        for (int s = 0; s < 6; ++s) wB[s] = *(const short8*)(bw + 32 * s);
    }

    int ep = 0;
    for (int t = 0; t < Tt; ++t) {
        const int parP = (t - 1) & 1, parC = t & 1;

        // ---- per-column BN scale/shift from partials(t-1) ----
        if (t > 0) {
            const float* ps = Pst + ((size_t)parP * 2 + 0) * 16 * 512 + tid;
            const float* pq = Pst + ((size_t)parP * 2 + 1) * 16 * 512 + tid;
            float s1 = 0.f, s2 = 0.f;
            #pragma unroll
            for (int i = 0; i < 16; ++i) { s1 += ps[i * 512]; s2 += pq[i * 512]; }
            const float mu = s1 * (1.f / 256.f);
            const float var = fmaxf(s2 * (1.f / 256.f) - mu * mu, 0.f);
            const float sc = bn_g[tid] * rsqrtf(var + EPS_BN);
            scs[tid] = sc; shs[tid] = bn_b[tid] - mu * sc;
        }
        // ---- stage [Xe|Ma] tile ----
        {
            const int r = tid >> 5, c8 = (tid & 31) * 8;
            const short* src = (c8 < 128)
                ? (Xe + ((size_t)t * Bb + m0 + r) * Ii + c8)
                : (Ma + ((size_t)t * Bb + m0 + r) * Ii + (c8 - 128));
            const short8 v = *(const short8*)src;
            *(short8*)((char*)sXM + ((r * 512 + c8 * 2) ^ ((r & 7) << 4))) = v;
        }
        __syncthreads();
        // ---- stage hp = (Hraw_prev * sc + sh) * gamma_h(t) ----
        {
            const int r = tid >> 5, cc = (tid & 31) * 16;
            short hv[16];
            if (t > 0) {
                const float* hr = Hraw + (size_t)parP * Bb * Hh + (size_t)(m0 + r) * Hh + cc;
                const short* gh = Ghb + ((size_t)t * Bb + m0 + r) * Hh + cc;
                #pragma unroll
                for (int i = 0; i < 16; ++i) {
                    const float h = fmaf(hr[i], scs[cc + i], shs[cc + i]);
                    hv[i] = f2bf(h * bf2f(gh[i]));
                }
            } else {
                #pragma unroll
                for (int i = 0; i < 16; ++i) hv[i] = 0;
            }
            char* dst = (char*)sH;
            const int off0 = r * 1024 + cc * 2;
            *(short8*)(dst + ((off0) ^ ((r & 7) << 4))) = *(short8*)&hv[0];
            *(short8*)(dst + ((off0 + 16) ^ ((r & 7) << 4))) = *(short8*)&hv[8];
        }
        __syncthreads();

        // ================= Phase A GEMM: [Xe|Ma|hp] @ Wc1 ==================
        f32x4 acc = (f32x4){0.f, 0.f, 0.f, 0.f};
        #pragma unroll
        for (int s = 0; s < 12; ++s) {
            const int k = kh * 384 + 32 * s;
            const char* bp; int off;
            if (k < 256) { bp = (const char*)sXM; off = c * 512 + (k + 8 * g) * 2; }
            else         { bp = (const char*)sH;  off = c * 1024 + (k - 256 + 8 * g) * 2; }
            const short8 a = *(const short8*)(bp + (off ^ ((c & 7) << 4)));
            acc = mfma_bf16(a, wA[s], acc);
        }
        if (kh == 1) {
            float* sp = scratch + (aA * 64 + lane) * 4;
            sp[0] = acc[0]; sp[1] = acc[1]; sp[2] = acc[2]; sp[3] = acc[3];
        }
        __syncthreads();
        if (kh == 0) {
            const float* sp = scratch + (aA * 64 + lane) * 4;
            acc[0] += sp[0]; acc[1] += sp[1]; acc[2] += sp[2]; acc[3] += sp[3];
            const int n = n0A + c;
            const float bs = bias1[n];
            #pragma unroll
            for (int j = 0; j < 4; ++j) {
                const int m = m0 + 4 * g + j;
                const float v = sigmoidf_(acc[j] + bs);
                if (n < Hh) {
                    Zbuf[(size_t)m * Hh + n] = v;
                } else {
                    const int nn = n - Hh;
                    const int row = 4 * g + j;
                    const short hp = *(const short*)((const char*)sH +
                        ((row * 1024 + nn * 2) ^ ((row & 7) << 4)));
                    RH[(size_t)m * Hh + nn] = f2bf(v * bf2f(hp));
                }
            }
        }
        // ---- arrive bar1 ----
        ep += 1;
        __syncthreads();
        if (tid == 0)
            __hip_atomic_store(&barr[bid * 16], ep, __ATOMIC_RELEASE, __HIP_MEMORY_SCOPE_AGENT);
        // ---- fuzzy-barrier duty: out_hs[t-1] + ys[t-1] (row = bid) ----
        if (t > 0) {
            const float* hr = Hraw + (size_t)parP * Bb * Hh + (size_t)bid * Hh;
            const float h = fmaf(hr[tid], scs[tid], shs[tid]);
            out_hs[((size_t)bid * Tt + (t - 1)) * Hh + tid] = h;
            float p0 = h * Why[2 * tid], p1 = h * Why[2 * tid + 1];
            #pragma unroll
            for (int s = 1; s < 64; s <<= 1) { p0 += __shfl_xor(p0, s); p1 += __shfl_xor(p1, s); }
            if (lane == 0) { ysred[w * 2] = p0; ysred[w * 2 + 1] = p1; }
            __syncthreads();
            if (tid == 0) {
                float q0 = 0.f, q1 = 0.f;
                #pragma unroll
                for (int i = 0; i < 8; ++i) { q0 += ysred[2 * i]; q1 += ysred[2 * i + 1]; }
                out_ys[((size_t)bid * Tt + (t - 1)) * Oo + 0] = softplusf_(q0 + bhy[0]);
                out_ys[((size_t)bid * Tt + (t - 1)) * Oo + 1] = softplusf_(q1 + bhy[1]);
            }
        }
        // ---- wait bar1 ----
        if (tid < 256) {
            while (__hip_atomic_load(&barr[tid * 16], __ATOMIC_RELAXED, __HIP_MEMORY_SCOPE_AGENT) < ep)
                __builtin_amdgcn_s_sleep(1);
        }
        __syncthreads();
        if (tid == 0)
            (void)__hip_atomic_load(&barr[0], __ATOMIC_ACQUIRE, __HIP_MEMORY_SCOPE_AGENT);
        __syncthreads();

        // ================= Phase B: [Xe|Ma|RH] @ Wc2 =======================
        {
            const int r = tid >> 5, cc = (tid & 31) * 16;
            const short8 v0 = *(const short8*)(RH + (size_t)(m0 + r) * Hh + cc);
            const short8 v1 = *(const short8*)(RH + (size_t)(m0 + r) * Hh + cc + 8);
            char* dst = (char*)sRH;
            const int off0 = r * 1024 + cc * 2;
            *(short8*)(dst + ((off0) ^ ((r & 7) << 4))) = v0;
            *(short8*)(dst + ((off0 + 16) ^ ((r & 7) << 4))) = v1;
        }
        __syncthreads();
        f32x4 accB = (f32x4){0.f, 0.f, 0.f, 0.f};
        #pragma unroll
        for (int s = 0; s < 6; ++s) {
            const int k = kq * 192 + 32 * s;
            const char* bp; int off;
            if (k < 256) { bp = (const char*)sXM; off = c * 512 + (k + 8 * g) * 2; }
            else         { bp = (const char*)sRH; off = c * 1024 + (k - 256 + 8 * g) * 2; }
            const short8 a = *(const short8*)(bp + (off ^ ((c & 7) << 4)));
            accB = mfma_bf16(a, wB[s], accB);
        }
        if (kq > 0) {
            float* sp = scratch + ((bB * 3 + (kq - 1)) * 64 + lane) * 4;
            sp[0] = accB[0]; sp[1] = accB[1]; sp[2] = accB[2]; sp[3] = accB[3];
        }
        __syncthreads();
        if (kq == 0) {
            #pragma unroll
            for (int qq = 0; qq < 3; ++qq) {
                const float* sp = scratch + ((bB * 3 + qq) * 64 + lane) * 4;
                accB[0] += sp[0]; accB[1] += sp[1]; accB[2] += sp[2]; accB[3] += sp[3];
            }
            const int n = n0B + c;
            const float bh_ = b_h[n];
            float sp_ = 0.f, sq_ = 0.f;
            #pragma unroll
            for (int j = 0; j < 4; ++j) {
                const int m = m0 + 4 * g + j;
                const int row = 4 * g + j;
                const float pre = accB[j] + bh_;
                const float z = Zbuf[(size_t)m * Hh + n];
                const short hpb = *(const short*)((const char*)sH +
                    ((row * 1024 + n * 2) ^ ((row & 7) << 4)));
                const float hp = bf2f(hpb);
                const float hr = (1.f - z) * hp + z * tanhf(pre);
                Hraw[(size_t)parC * Bb * Hh + (size_t)m * Hh + n] = hr;
                sp_ += hr; sq_ += hr * hr;
            }
            sp_ += __shfl_xor(sp_, 16); sp_ += __shfl_xor(sp_, 32);
            sq_ += __shfl_xor(sq_, 16); sq_ += __shfl_xor(sq_, 32);
            if (lane < 16) {
                Pst[((size_t)parC * 2 + 0) * 16 * 512 + mt * 512 + n0B + lane] = sp_;
                Pst[((size_t)parC * 2 + 1) * 16 * 512 + mt * 512 + n0B + lane] = sq_;
            }
        }
        // ---- arrive + wait bar2 ----
        ep += 1;
        __syncthreads();
        if (tid == 0)
            __hip_atomic_store(&barr[bid * 16], ep, __ATOMIC_RELEASE, __HIP_MEMORY_SCOPE_AGENT);
        if (tid < 256) {
            while (__hip_atomic_load(&barr[tid * 16], __ATOMIC_RELAXED, __HIP_MEMORY_SCOPE_AGENT) < ep)
                __builtin_amdgcn_s_sleep(1);
        }
        __syncthreads();
        if (tid == 0)
            (void)__hip_atomic_load(&barr[0], __ATOMIC_ACQUIRE, __HIP_MEMORY_SCOPE_AGENT);
        __syncthreads();
    }

    // ---- tail: out_hs / ys for t = Tt-1 ----
    {
        const int parP = (Tt - 1) & 1;
        {
            const float* ps = Pst + ((size_t)parP * 2 + 0) * 16 * 512 + tid;
            const float* pq = Pst + ((size_t)parP * 2 + 1) * 16 * 512 + tid;
            float s1 = 0.f, s2 = 0.f;
            #pragma unroll
            for (int i = 0; i < 16; ++i) { s1 += ps[i * 512]; s2 += pq[i * 512]; }
            const float mu = s1 * (1.f / 256.f);
            const float var = fmaxf(s2 * (1.f / 256.f) - mu * mu, 0.f);
            const float sc = bn_g[tid] * rsqrtf(var + EPS_BN);
            scs[tid] = sc; shs[tid] = bn_b[tid] - mu * sc;
        }
        __syncthreads();
        const float* hr = Hraw + (size_t)parP * Bb * Hh + (size_t)bid * Hh;
        const float h = fmaf(hr[tid], scs[tid], shs[tid]);
        out_hs[((size_t)bid * Tt + (Tt - 1)) * Hh + tid] = h;
        float p0 = h * Why[2 * tid], p1 = h * Why[2 * tid + 1];
        #pragma unroll
        for (int s = 1; s < 64; s <<= 1) { p0 += __shfl_xor(p0, s); p1 += __shfl_xor(p1, s); }
        if (lane == 0) { ysred[w * 2] = p0; ysred[w * 2 + 1] = p1; }
        __syncthreads();
        if (tid == 0) {
            float q0 = 0.f, q1 = 0.f;
            #pragma unroll
            for (int i = 0; i < 8; ++i) { q0 += ysred[2 * i]; q1 += ysred[2 * i + 1]; }
            out_ys[((size_t)bid * Tt + (Tt - 1)) * Oo + 0] = softplusf_(q0 + bhy[0]);
            out_ys[((size_t)bid * Tt + (Tt - 1)) * Oo + 1] = softplusf_(q1 + bhy[1]);
        }
    }
}

// ---------------------------------------------------------------------------
extern "C" void kernel_launch(void* const* d_in, const int* in_sizes, int n_in,
                              void* d_out, int out_size, void* d_ws, size_t ws_size,
                              hipStream_t stream)
{
    const float* input  = (const float*)d_in[0];
    const float* xmean  = (const float*)d_in[1];
    const float* W_dg_x = (const float*)d_in[2];
    const float* b_dg_x = (const float*)d_in[3];
    const float* W_dg_h = (const float*)d_in[4];
    const float* b_dg_h = (const float*)d_in[5];
    const float* W_xz   = (const float*)d_in[6];
    const float* W_hz   = (const float*)d_in[7];
    const float* W_mz   = (const float*)d_in[8];
    const float* b_z    = (const float*)d_in[9];
    const float* W_xr   = (const float*)d_in[10];
    const float* W_hr   = (const float*)d_in[11];
    const float* W_mr   = (const float*)d_in[12];
    const float* b_r    = (const float*)d_in[13];
    const float* W_xh   = (const float*)d_in[14];
    const float* W_hh   = (const float*)d_in[15];
    const float* W_mh   = (const float*)d_in[16];
    const float* b_h    = (const float*)d_in[17];
    const float* W_hy   = (const float*)d_in[18];
    const float* b_hy   = (const float*)d_in[19];
    const float* bn_g   = (const float*)d_in[20];
    const float* bn_b   = (const float*)d_in[21];

    float* out_ys = (float*)d_out;
    float* out_hs = out_ys + (size_t)Bb * Tt * Oo;

    char* p = (char*)d_ws;
    float* Xall = (float*)p;            p += (size_t)TBr * Ii * 4;
    short* Mall = (short*)p;            p += (size_t)TBr * Ii * 2;
    short* Dall = (short*)p;            p += (size_t)TBr * Ii * 2;
    short* Gxb  = (short*)p;            p += (size_t)TBr * Ii * 2;
    short* Ghb  = (short*)p;            p += (size_t)TBr * Hh * 2;
    short* Xe   = (short*)p;            p += (size_t)TBr * Ii * 2;
    short* Wc1T = (short*)p;            p += (size_t)1024 * 768 * 2;
    short* Wc2T = (short*)p;            p += (size_t)512 * 768 * 2;
    short* WdgxT= (short*)p;            p += (size_t)128 * 128 * 2;
    short* WdghT= (short*)p;            p += (size_t)512 * 128 * 2;
    float* bias1= (float*)p;            p += 1024 * 4;
    float* Zbuf = (float*)p;            p += (size_t)Bb * Hh * 4;
    short* RH   = (short*)p;            p += (size_t)Bb * Hh * 2;
    float* Hraw = (float*)p;            p += (size_t)2 * Bb * Hh * 4;
    float* Pst  = (float*)p;            p += (size_t)2 * 2 * 16 * 512 * 4;
    int*   barr = (int*)p;              p += 256 * 16 * 4;

    hipMemsetAsync(barr, 0, 256 * 16 * 4, stream);

    repack_kernel<<<dim3(Tt / 32, Ii / 32, Bb * 3), dim3(32, 32), 0, stream>>>(input, Xall, Mall, Dall);

    {
        const int total = 1024 * 768 + 512 * 768 + 128 * 128 + 512 * 128 + 1024;
        pack_weights_kernel<<<(total + 255) / 256, 256, 0, stream>>>(
            W_dg_x, W_dg_h,
            W_xz, W_hz, W_mz, b_z,
            W_xr, W_hr, W_mr, b_r,
            W_xh, W_hh, W_mh,
            Wc1T, Wc2T, WdgxT, WdghT, bias1);
    }

    gdecay_kernel<<<dim3(TBr / 32, Ii / 64), 64, 0, stream>>>(Dall, WdgxT, b_dg_x, Gxb, Ii);
    gdecay_kernel<<<dim3(TBr / 32, Hh / 64), 64, 0, stream>>>(Dall, WdghT, b_dg_h, Ghb, Hh);

    xeff_scan_kernel<<<(Bb * Ii) / 256, 256, 0, stream>>>(Xall, Mall, Gxb, xmean, Xe);

    grud_persistent<<<256, 512, 0, stream>>>(
        Xe, Mall, Ghb, Wc1T, Wc2T, bias1, b_h, bn_g, bn_b,
        W_hy, b_hy, Zbuf, RH, Hraw, Pst,
        out_hs, out_ys, barr);
}